// Round 2
// baseline (2623.599 us; speedup 1.0000x reference)
//
#include <hip/hip_runtime.h>
#include <hip/hip_bf16.h>

// Problem sizes (fixed)
constexpr int B   = 256;
constexpr int M   = 2048;
constexpr int E   = 128;
constexpr int IN  = 512;
constexpr int Qd  = 512;
constexpr int OUTd= 512;
constexpr int H   = 64;

// Output element offsets (same element layout for bf16 or f32 outputs)
constexpr size_t OFF_WR = 0;
constexpr size_t OFF_W  = (size_t)B*M;
constexpr size_t OFF_U  = (size_t)2*B*M;
constexpr size_t OFF_Y  = (size_t)3*B*M;
constexpr size_t OFF_NM = OFF_Y + (size_t)B*OUTd;

// ---------- bf16 helpers ----------
__device__ __forceinline__ float bf2f(unsigned short u) {
    union { unsigned int i; float f; } v; v.i = ((unsigned int)u) << 16; return v.f;
}
__device__ __forceinline__ unsigned short f2bf(float f) {
    unsigned int x = __float_as_uint(f);
    unsigned int r = (x + 0x7fffu + ((x >> 16) & 1u)) >> 16;   // RNE
    return (unsigned short)r;
}
__device__ __forceinline__ void unpack8(uint4 d, float* o) {
    o[0]=bf2f(d.x & 0xffff); o[1]=bf2f(d.x >> 16);
    o[2]=bf2f(d.y & 0xffff); o[3]=bf2f(d.y >> 16);
    o[4]=bf2f(d.z & 0xffff); o[5]=bf2f(d.z >> 16);
    o[6]=bf2f(d.w & 0xffff); o[7]=bf2f(d.w >> 16);
}
__device__ __forceinline__ uint4 pack8(const float* f) {
    uint4 d;
    d.x = (unsigned)f2bf(f[0]) | ((unsigned)f2bf(f[1]) << 16);
    d.y = (unsigned)f2bf(f[2]) | ((unsigned)f2bf(f[3]) << 16);
    d.z = (unsigned)f2bf(f[4]) | ((unsigned)f2bf(f[5]) << 16);
    d.w = (unsigned)f2bf(f[6]) | ((unsigned)f2bf(f[7]) << 16);
    return d;
}

// ---------- dual-dtype load/store (bf = 1 -> bf16, 0 -> f32); wave-uniform branch ----------
__device__ __forceinline__ float ldf(const void* p, size_t i, int bf) {
    return bf ? bf2f(((const unsigned short*)p)[i]) : ((const float*)p)[i];
}
__device__ __forceinline__ void ld8(const void* p, size_t i, int bf, float* o) {
    if (bf) {
        uint4 d = *(const uint4*)((const unsigned short*)p + i);
        unpack8(d, o);
    } else {
        const float4* q = (const float4*)((const float*)p + i);
        float4 a = q[0], c = q[1];
        o[0]=a.x; o[1]=a.y; o[2]=a.z; o[3]=a.w;
        o[4]=c.x; o[5]=c.y; o[6]=c.z; o[7]=c.w;
    }
}
__device__ __forceinline__ void st1(void* p, size_t i, int bf, float v) {
    if (bf) ((unsigned short*)p)[i] = f2bf(v);
    else    ((float*)p)[i] = v;
}
__device__ __forceinline__ void st8(void* p, size_t i, int bf, const float* v) {
    if (bf) {
        *(uint4*)((unsigned short*)p + i) = pack8(v);
    } else {
        float4 a, c;
        a.x=v[0]; a.y=v[1]; a.z=v[2]; a.w=v[3];
        c.x=v[4]; c.y=v[5]; c.z=v[6]; c.w=v[7];
        float4* q = (float4*)((float*)p + i);
        q[0]=a; q[1]=c;
    }
}

// ---------- inline dtype detector (per-wave ballot over first 512 u16 of usage) ----------
// f32 uniform[0,1): odd u16 halves decode in-range, even halves ~25% -> per-lane
// all-8-in-range prob ~0.4% => ~0 lanes pass. bf16: all 64 lanes pass. Threshold 32.
__device__ __forceinline__ int detect_bf(const void* usage) {
    const int lane = threadIdx.x & 63;
    uint4 d = ((const uint4*)usage)[lane];   // 8 u16 entries
    float o[8]; unpack8(d, o);
    bool ok = true;
    #pragma unroll
    for (int j = 0; j < 8; ++j) ok = ok && (o[j] >= 0.0f && o[j] <= 1.0f);
    unsigned long long m = __ballot(ok);
    return (__popcll(m) >= 32) ? 1 : 0;
}

// ---------- kA: blocks [0,B): per-batch precompute (k1); blocks [B,2B): allocation ----------
__global__ __launch_bounds__(256) void kA_pre_alloc(
    const void* __restrict__ x,   const void* __restrict__ qy,
    const void* __restrict__ I_w, const void* __restrict__ I_b,
    const void* __restrict__ W1w, const void* __restrict__ W1b,
    const void* __restrict__ W2w, const void* __restrict__ W2b,
    const void* __restrict__ R1w, const void* __restrict__ R1b,
    const void* __restrict__ R2w, const void* __restrict__ R2b,
    const void* __restrict__ rw,  const void* __restrict__ ww,
    const void* __restrict__ us,  const void* __restrict__ fg,
    float* __restrict__ emb_ws, float* __restrict__ v_ws, float* __restrict__ u2_ws,
    float* __restrict__ c1_ws,  float* __restrict__ c2_ws,
    float* __restrict__ alloc_ws, void* __restrict__ dout)
{
    __shared__ unsigned long long sh64[M];   // 16 KB (sort path; aliased as floats in k1 path)
    __shared__ float scan[256];
    const int bf = detect_bf(us);
    const int t = threadIdx.x;

    if (blockIdx.x < B) {
        // ================= k1 precompute path =================
        const int b = blockIdx.x;
        float* fsm  = (float*)sh64;          // 4096 floats available
        float* xs   = fsm;                   // 512
        float* qs   = fsm + 512;             // 512
        float* embs = fsm + 1024;            // 128
        float* wis  = fsm + 1152;            // 64
        float* rqs  = fsm + 1216;            // 64
        float* red  = scan;                  // 256

        for (int i = t; i < IN; i += 256) xs[i] = ldf(x,  (size_t)b*IN + i, bf);
        for (int i = t; i < Qd; i += 256) qs[i] = ldf(qy, (size_t)b*Qd + i, bf);
        __syncthreads();

        // phase 1: emb[t<128] || Rq[t2<64]
        if (t < 128) {
            float acc = 0.f;
            for (int c = 0; c < IN/8; ++c) {
                float m8[8]; ld8(I_w, (size_t)t*IN + c*8, bf, m8);
                #pragma unroll
                for (int j = 0; j < 8; ++j) acc += m8[j] * xs[c*8 + j];
            }
            acc += ldf(I_b, t, bf);
            embs[t] = acc;
            emb_ws[(size_t)b*E + t] = acc;
        } else {
            int t2 = t - 128;
            if (t2 < H) {
                float rv = 0.f;
                for (int c = 0; c < Qd/8; ++c) {
                    float m8[8]; ld8(R1w, (size_t)t2*Qd + c*8, bf, m8);
                    #pragma unroll
                    for (int j = 0; j < 8; ++j) rv += m8[j] * qs[c*8 + j];
                }
                rv += ldf(R1b, t2, bf);
                rqs[t2] = rv;
            }
        }
        __syncthreads();

        // phase 2: Wi[t<64] || u2[t2<128] + c2 partials
        if (t < H) {
            float wv = 0.f;
            for (int c = 0; c < E/8; ++c) {
                float m8[8]; ld8(W1w, (size_t)t*E + c*8, bf, m8);
                #pragma unroll
                for (int j = 0; j < 8; ++j) wv += m8[j] * embs[c*8 + j];
            }
            wv += ldf(W1b, t, bf);
            wis[t] = wv;
        } else if (t >= 128) {
            int t2 = t - 128;
            float uu = 0.f;
            for (int h = 0; h < H; ++h) uu += ldf(R2w, (size_t)h*E + t2, bf) * rqs[h];
            u2_ws[(size_t)b*E + t2] = uu;
            red[t] = (t2 < H) ? rqs[t2] * ldf(R2b, t2, bf) : 0.f;
        }
        __syncthreads();

        // phase 3: v[t<128] + c1 partials
        if (t < 128) {
            float vv = 0.f;
            for (int h = 0; h < H; ++h) vv += ldf(W2w, (size_t)h*E + t, bf) * wis[h];
            v_ws[(size_t)b*E + t] = vv;
            red[t] = (t < H) ? wis[t] * ldf(W2b, t, bf) : 0.f;
        }
        __syncthreads();

        // dual half-reductions: red[0:128) -> c1, red[128:256) -> c2
        for (int off = 64; off > 0; off >>= 1) {
            if (t < off) red[t] += red[t + off];
            if (t >= 128 && t < 128 + off) red[t] += red[t + off];
            __syncthreads();
        }
        if (t == 0)   c1_ws[b] = red[0];
        if (t == 128) c2_ws[b] = red[128];

    } else {
        // ================= allocation path (register bitonic) =================
        const int b = blockIdx.x - B;
        const size_t base = (size_t)b*M + (size_t)t*8;
        float r8[8], w8[8], u8[8], f8[8], nu[8];
        ld8(rw, base, bf, r8); ld8(ww, base, bf, w8);
        ld8(us, base, bf, u8); ld8(fg, base, bf, f8);

        unsigned long long key[8];
        #pragma unroll
        for (int q = 0; q < 8; ++q) {
            float u = 1e-5f + (1.0f - 1e-5f) * u8[q];
            float psi = 1.0f - f8[q] * r8[q];
            u = u + w8[q] - u * w8[q];
            u = u * psi;
            nu[q] = u;
            unsigned fb = __float_as_uint(u);
            fb = (fb & 0x80000000u) ? ~fb : (fb | 0x80000000u);
            key[q] = ((unsigned long long)fb << 32) | (unsigned)(t*8 + q);
        }
        st8(dout, OFF_U + base, bf, nu);          // new_usage output

        // Bitonic sort ascending on uint64 keys, 8 elems/thread (i = t*8+q)
        for (int k = 2; k <= M; k <<= 1) {
            for (int j = k >> 1; j > 0; j >>= 1) {
                if (j >= 512) {
                    __syncthreads();
                    #pragma unroll
                    for (int q = 0; q < 8; ++q) sh64[t*8 + q] = key[q];
                    __syncthreads();
                    const bool up      = (((t << 3) & k) == 0);
                    const bool lower   = (((t << 3) & j) == 0);
                    const bool keepmin = (lower == up);
                    #pragma unroll
                    for (int q = 0; q < 8; ++q) {
                        unsigned long long o = sh64[(t*8 + q) ^ j];
                        bool take = keepmin ? (o < key[q]) : (o > key[q]);
                        if (take) key[q] = o;
                    }
                } else if (j >= 8) {
                    const int d = j >> 3;
                    const bool up      = (((t << 3) & k) == 0);
                    const bool keepmin = (((t & d) == 0) == up);
                    #pragma unroll
                    for (int q = 0; q < 8; ++q) {
                        unsigned long long o = __shfl_xor(key[q], d, 64);
                        bool take = keepmin ? (o < key[q]) : (o > key[q]);
                        if (take) key[q] = o;
                    }
                } else {
                    #pragma unroll
                    for (int q = 0; q < 8; ++q) {
                        if (!(q & j)) {
                            int p = q | j;
                            bool up = ((((t << 3) + q) & k) == 0);
                            unsigned long long a = key[q], c = key[p];
                            bool sw = up ? (a > c) : (a < c);
                            if (sw) { key[q] = c; key[p] = a; }
                        }
                    }
                }
            }
        }

        // extract sorted (u, idx); inclusive cumprod; scatter alloc
        float su[8], lp[8]; int sidx[8];
        #pragma unroll
        for (int q = 0; q < 8; ++q) {
            unsigned fb = (unsigned)(key[q] >> 32);
            fb = (fb & 0x80000000u) ? (fb ^ 0x80000000u) : ~fb;
            su[q]   = __uint_as_float(fb);
            sidx[q] = (int)(key[q] & 0xffffffffu);
        }
        float run = 1.f;
        #pragma unroll
        for (int q = 0; q < 8; ++q) { run *= su[q]; lp[q] = run; }
        scan[t] = run;
        __syncthreads();
        for (int off = 1; off < 256; off <<= 1) {
            float val = scan[t];
            float oth = (t >= off) ? scan[t - off] : 1.0f;
            __syncthreads();
            scan[t] = val * oth;
            __syncthreads();
        }
        float pref = (t > 0) ? scan[t - 1] : 1.0f;
        #pragma unroll
        for (int q = 0; q < 8; ++q)
            alloc_ws[(size_t)b*M + sidx[q]] = (1.0f - su[q]) * (pref * lp[q]);
    }
}

// ---------- kS: scores per (b,chunk); last chunk block per batch runs softmax chain ----------
__global__ __launch_bounds__(256) void kS_scores_weights(
    const void* __restrict__ mem, const void* __restrict__ us,
    const float* __restrict__ v_ws, const float* __restrict__ u2_ws,
    const float* __restrict__ c1_ws, const float* __restrict__ c2_ws,
    const float* __restrict__ emb_ws, const float* __restrict__ alloc_ws,
    float* __restrict__ s1, float* __restrict__ s2,
    float* __restrict__ w_ws, float* __restrict__ wr_ws,
    int* __restrict__ cnt1, void* __restrict__ dout)
{
    __shared__ float red[256];
    __shared__ int isLast;
    const int bf = detect_bf(us);
    const int blk = blockIdx.x;
    const int b = blk >> 4, chunk = blk & 15;
    const int t = threadIdx.x, l = t & 15, g = t >> 4;

    // ---- scores: s1 = v.mem + c1, s2 = u2.mem ----
    {
        float v8[8], u8[8];
        const float* vb = v_ws  + (size_t)b*E + l*8;
        const float* ub = u2_ws + (size_t)b*E + l*8;
        #pragma unroll
        for (int j = 0; j < 8; ++j) { v8[j] = vb[j]; u8[j] = ub[j]; }
        const float cc1 = c1_ws[b];
        const size_t mbase = (size_t)b*M*E;
        const int row0 = chunk*128 + g;
        for (int it = 0; it < 8; ++it) {
            int row = row0 + it*16;
            float m8[8]; ld8(mem, mbase + (size_t)row*E + l*8, bf, m8);
            float p1 = 0.f, p2 = 0.f;
            #pragma unroll
            for (int j = 0; j < 8; ++j) { p1 += m8[j]*v8[j]; p2 += m8[j]*u8[j]; }
            #pragma unroll
            for (int mask = 8; mask > 0; mask >>= 1) {
                p1 += __shfl_xor(p1, mask, 16);
                p2 += __shfl_xor(p2, mask, 16);
            }
            if (l == 0) {
                s1[(size_t)b*M + row] = p1 + cc1;
                s2[(size_t)b*M + row] = p2;
            }
        }
    }

    // ---- last-block rendezvous ----
    __threadfence();
    __syncthreads();
    if (t == 0) isLast = (atomicAdd(&cnt1[b], 1) == 15) ? 1 : 0;
    __syncthreads();
    if (!isLast) return;
    __threadfence();

    // ---- softmax chain (former k4) for batch b ----
    const float* s1b = s1 + (size_t)b*M;
    const float* s2b = s2 + (size_t)b*M;

    // d2 = dot(u2, emb) over E=128
    red[t] = (t < E) ? u2_ws[(size_t)b*E + t] * emb_ws[(size_t)b*E + t] : 0.f;
    __syncthreads();
    for (int off = 128; off > 0; off >>= 1) { if (t < off) red[t] += red[t+off]; __syncthreads(); }
    const float dd = red[0];
    const float cc = c2_ws[b];
    __syncthreads();

    float sv[8];
    float lmax = -3.4e38f;
    #pragma unroll
    for (int s = 0; s < 8; ++s) { sv[s] = s1b[s*256 + t]; lmax = fmaxf(lmax, sv[s]); }
    red[t] = lmax; __syncthreads();
    for (int off = 128; off > 0; off >>= 1) { if (t < off) red[t] = fmaxf(red[t], red[t+off]); __syncthreads(); }
    float gmax = red[0]; __syncthreads();

    float lsum = 0.f;
    #pragma unroll
    for (int s = 0; s < 8; ++s) { float e = expf(sv[s] - gmax); sv[s] = e; lsum += e; }
    red[t] = lsum; __syncthreads();
    for (int off = 128; off > 0; off >>= 1) { if (t < off) red[t] += red[t+off]; __syncthreads(); }
    float inv = 1.0f / red[0]; __syncthreads();

    float rs[8];
    #pragma unroll
    for (int s = 0; s < 8; ++s) {
        int m = s*256 + t;
        float wc = sv[s] * inv;
        float wv = 0.5f * (wc + alloc_ws[(size_t)b*M + m]);
        w_ws[(size_t)b*M + m] = wv;
        st1(dout, OFF_W + (size_t)b*M + m, bf, wv);   // new_write_weights
        rs[s] = s2b[m] + wv * dd + cc;
    }

    lmax = -3.4e38f;
    #pragma unroll
    for (int s = 0; s < 8; ++s) lmax = fmaxf(lmax, rs[s]);
    red[t] = lmax; __syncthreads();
    for (int off = 128; off > 0; off >>= 1) { if (t < off) red[t] = fmaxf(red[t], red[t+off]); __syncthreads(); }
    gmax = red[0]; __syncthreads();

    lsum = 0.f;
    #pragma unroll
    for (int s = 0; s < 8; ++s) { float e = expf(rs[s] - gmax); rs[s] = e; lsum += e; }
    red[t] = lsum; __syncthreads();
    for (int off = 128; off > 0; off >>= 1) { if (t < off) red[t] += red[t+off]; __syncthreads(); }
    float inv2 = 1.0f / red[0]; __syncthreads();

    #pragma unroll
    for (int s = 0; s < 8; ++s) {
        int m = s*256 + t;
        float wrv = rs[s] * inv2;
        wr_ws[(size_t)b*M + m] = wrv;
        st1(dout, OFF_WR + (size_t)b*M + m, bf, wrv); // wr
    }
}

// ---------- kU: memory update per (b,chunk); last chunk block per batch runs output ----------
__global__ __launch_bounds__(256) void kU_update_out(
    const void* __restrict__ mem, const void* __restrict__ us,
    const float* __restrict__ emb_ws,
    const float* __restrict__ w_ws, const float* __restrict__ wr_ws,
    float* __restrict__ pooled_p, int* __restrict__ cnt2,
    const void* __restrict__ O_w, const void* __restrict__ O_b,
    void* __restrict__ dout)
{
    __shared__ float pw[4][E];
    __shared__ float ps[E];
    __shared__ int isLast;
    const int bf = detect_bf(us);
    const int blk = blockIdx.x;
    const int b = blk >> 4, chunk = blk & 15;
    const int t = threadIdx.x, l = t & 15, g = t >> 4;

    float e8[8];
    {
        const float* eb = emb_ws + (size_t)b*E + l*8;
        #pragma unroll
        for (int j = 0; j < 8; ++j) e8[j] = eb[j];
    }
    float acc[8] = {0,0,0,0,0,0,0,0};
    const size_t mbase = (size_t)b*M*E;
    const int row0 = chunk*128 + g;
    for (int it = 0; it < 8; ++it) {
        int row = row0 + it*16;
        size_t off = mbase + (size_t)row*E + l*8;
        float m8[8]; ld8(mem, off, bf, m8);
        float wv  = w_ws [(size_t)b*M + row];
        float wrv = wr_ws[(size_t)b*M + row];
        float n8[8];
        #pragma unroll
        for (int j = 0; j < 8; ++j) {
            n8[j] = m8[j] + wv * e8[j];
            acc[j] += wrv * n8[j];
        }
        st8(dout, OFF_NM + off, bf, n8);          // new_memory output
    }
    // reduce over the 16 g-groups: 4 in-wave via shfl, 4 waves via LDS
    #pragma unroll
    for (int j = 0; j < 8; ++j) {
        acc[j] += __shfl_xor(acc[j], 16, 64);
        acc[j] += __shfl_xor(acc[j], 32, 64);
    }
    const int wid = t >> 6;
    if ((t & 63) < 16) {
        const int l0 = t & 15;
        #pragma unroll
        for (int j = 0; j < 8; ++j) pw[wid][l0*8 + j] = acc[j];
    }
    __syncthreads();
    if (t < E)
        pooled_p[((size_t)b*16 + chunk)*E + t] = pw[0][t] + pw[1][t] + pw[2][t] + pw[3][t];

    // ---- last-block rendezvous ----
    __threadfence();
    __syncthreads();
    if (t == 0) isLast = (atomicAdd(&cnt2[b], 1) == 15) ? 1 : 0;
    __syncthreads();
    if (!isLast) return;
    __threadfence();

    // ---- former k6: pooled = sum chunks; output = pooled @ O_w^T + O_b ----
    if (t < E) {
        float s = 0.f;
        #pragma unroll
        for (int c = 0; c < 16; ++c) s += pooled_p[((size_t)b*16 + c)*E + t];
        ps[t] = s;
    }
    __syncthreads();
    for (int o = t; o < OUTd; o += 256) {
        float a = 0.f;
        for (int c = 0; c < E/8; ++c) {
            float m8[8]; ld8(O_w, (size_t)o*E + c*8, bf, m8);
            #pragma unroll
            for (int j = 0; j < 8; ++j) a += m8[j] * ps[c*8 + j];
        }
        a += ldf(O_b, o, bf);
        st1(dout, OFF_Y + (size_t)b*OUTd + o, bf, a);
    }
}

extern "C" void kernel_launch(void* const* d_in, const int* in_sizes, int n_in,
                              void* d_out, int out_size, void* d_ws, size_t ws_size,
                              hipStream_t stream)
{
    const void* rw  = d_in[0];
    const void* ww  = d_in[1];
    const void* us  = d_in[2];
    const void* fg  = d_in[3];
    const void* x   = d_in[4];
    const void* qy  = d_in[5];
    const void* mem = d_in[6];
    const void* I_w = d_in[7];
    const void* I_b = d_in[8];
    const void* W1w = d_in[9];
    const void* W1b = d_in[10];
    const void* W2w = d_in[11];
    const void* W2b = d_in[12];
    const void* R1w = d_in[13];
    const void* R1b = d_in[14];
    const void* R2w = d_in[15];
    const void* R2b = d_in[16];
    const void* O_w = d_in[17];
    const void* O_b = d_in[18];

    int*   cnt1 = (int*)d_ws;                         // B
    int*   cnt2 = cnt1 + B;                           // B
    float* fbase   = (float*)d_ws + 2*B;              // 2048B offset, 16B-aligned
    float* emb_ws   = fbase;                          // B*E
    float* v_ws     = emb_ws + (size_t)B*E;           // B*E
    float* u2_ws    = v_ws   + (size_t)B*E;           // B*E
    float* c1_ws    = u2_ws  + (size_t)B*E;           // B
    float* c2_ws    = c1_ws  + B;                     // B
    float* alloc_ws = c2_ws  + B;                     // B*M (reused as pooled_p after kS)
    float* s1_ws    = alloc_ws + (size_t)B*M;         // B*M
    float* s2_ws    = s1_ws    + (size_t)B*M;         // B*M
    float* w_ws     = s2_ws    + (size_t)B*M;         // B*M
    float* wr_ws    = w_ws     + (size_t)B*M;         // B*M
    float* pooled_p = alloc_ws;                       // B*16*E == B*M floats, alloc dead after kS

    hipMemsetAsync(d_ws, 0, 2*B*sizeof(int), stream); // zero rendezvous counters

    kA_pre_alloc<<<2*B, 256, 0, stream>>>(x, qy, I_w, I_b, W1w, W1b, W2w, W2b,
                                          R1w, R1b, R2w, R2b, rw, ww, us, fg,
                                          emb_ws, v_ws, u2_ws, c1_ws, c2_ws,
                                          alloc_ws, d_out);
    kS_scores_weights<<<B*16, 256, 0, stream>>>(mem, us, v_ws, u2_ws, c1_ws, c2_ws,
                                          emb_ws, alloc_ws, s1_ws, s2_ws,
                                          w_ws, wr_ws, cnt1, d_out);
    kU_update_out<<<B*16, 256, 0, stream>>>(mem, us, emb_ws, w_ws, wr_ws,
                                          pooled_p, cnt2, O_w, O_b, d_out);
}

// Round 3
// 684.994 us; speedup vs baseline: 3.8301x; 3.8301x over previous
//
#include <hip/hip_runtime.h>
#include <hip/hip_bf16.h>

// Problem sizes (fixed)
constexpr int B   = 256;
constexpr int M   = 2048;
constexpr int E   = 128;
constexpr int IN  = 512;
constexpr int Qd  = 512;
constexpr int OUTd= 512;
constexpr int H   = 64;

// Output element offsets (same element layout for bf16 or f32 outputs)
constexpr size_t OFF_WR = 0;
constexpr size_t OFF_W  = (size_t)B*M;
constexpr size_t OFF_U  = (size_t)2*B*M;
constexpr size_t OFF_Y  = (size_t)3*B*M;
constexpr size_t OFF_NM = OFF_Y + (size_t)B*OUTd;

// ---------- bf16 helpers ----------
__device__ __forceinline__ float bf2f(unsigned short u) {
    union { unsigned int i; float f; } v; v.i = ((unsigned int)u) << 16; return v.f;
}
__device__ __forceinline__ unsigned short f2bf(float f) {
    unsigned int x = __float_as_uint(f);
    unsigned int r = (x + 0x7fffu + ((x >> 16) & 1u)) >> 16;   // RNE
    return (unsigned short)r;
}
__device__ __forceinline__ void unpack8(uint4 d, float* o) {
    o[0]=bf2f(d.x & 0xffff); o[1]=bf2f(d.x >> 16);
    o[2]=bf2f(d.y & 0xffff); o[3]=bf2f(d.y >> 16);
    o[4]=bf2f(d.z & 0xffff); o[5]=bf2f(d.z >> 16);
    o[6]=bf2f(d.w & 0xffff); o[7]=bf2f(d.w >> 16);
}
__device__ __forceinline__ uint4 pack8(const float* f) {
    uint4 d;
    d.x = (unsigned)f2bf(f[0]) | ((unsigned)f2bf(f[1]) << 16);
    d.y = (unsigned)f2bf(f[2]) | ((unsigned)f2bf(f[3]) << 16);
    d.z = (unsigned)f2bf(f[4]) | ((unsigned)f2bf(f[5]) << 16);
    d.w = (unsigned)f2bf(f[6]) | ((unsigned)f2bf(f[7]) << 16);
    return d;
}

// ---------- dual-dtype load/store (bf = 1 -> bf16, 0 -> f32); wave-uniform branch ----------
__device__ __forceinline__ float ldf(const void* p, size_t i, int bf) {
    return bf ? bf2f(((const unsigned short*)p)[i]) : ((const float*)p)[i];
}
__device__ __forceinline__ void ld8(const void* p, size_t i, int bf, float* o) {
    if (bf) {
        uint4 d = *(const uint4*)((const unsigned short*)p + i);
        unpack8(d, o);
    } else {
        const float4* q = (const float4*)((const float*)p + i);
        float4 a = q[0], c = q[1];
        o[0]=a.x; o[1]=a.y; o[2]=a.z; o[3]=a.w;
        o[4]=c.x; o[5]=c.y; o[6]=c.z; o[7]=c.w;
    }
}
__device__ __forceinline__ void st1(void* p, size_t i, int bf, float v) {
    if (bf) ((unsigned short*)p)[i] = f2bf(v);
    else    ((float*)p)[i] = v;
}
__device__ __forceinline__ void st8(void* p, size_t i, int bf, const float* v) {
    if (bf) {
        *(uint4*)((unsigned short*)p + i) = pack8(v);
    } else {
        float4 a, c;
        a.x=v[0]; a.y=v[1]; a.z=v[2]; a.w=v[3];
        c.x=v[4]; c.y=v[5]; c.z=v[6]; c.w=v[7];
        float4* q = (float4*)((float*)p + i);
        q[0]=a; q[1]=c;
    }
}

// ---------- inline dtype detector (per-wave ballot over first 512 u16 of usage) ----------
__device__ __forceinline__ int detect_bf(const void* usage) {
    const int lane = threadIdx.x & 63;
    uint4 d = ((const uint4*)usage)[lane];   // 8 u16 entries
    float o[8]; unpack8(d, o);
    bool ok = true;
    #pragma unroll
    for (int j = 0; j < 8; ++j) ok = ok && (o[j] >= 0.0f && o[j] <= 1.0f);
    unsigned long long m = __ballot(ok);
    return (__popcll(m) >= 32) ? 1 : 0;
}

// ---------- block reductions (1024 threads = 16 waves), LDS scratch: float[17] ----------
__device__ __forceinline__ float blk_max(float v, float* red, int t) {
    #pragma unroll
    for (int m = 1; m < 64; m <<= 1) v = fmaxf(v, __shfl_xor(v, m, 64));
    if ((t & 63) == 0) red[t >> 6] = v;
    __syncthreads();
    if (t < 16) {
        float x = red[t];
        #pragma unroll
        for (int m = 1; m < 16; m <<= 1) x = fmaxf(x, __shfl_xor(x, m, 16));
        if (t == 0) red[16] = x;
    }
    __syncthreads();
    float r = red[16];
    __syncthreads();
    return r;
}
__device__ __forceinline__ float blk_sum(float v, float* red, int t) {
    #pragma unroll
    for (int m = 1; m < 64; m <<= 1) v += __shfl_xor(v, m, 64);
    if ((t & 63) == 0) red[t >> 6] = v;
    __syncthreads();
    if (t < 16) {
        float x = red[t];
        #pragma unroll
        for (int m = 1; m < 16; m <<= 1) x += __shfl_xor(x, m, 16);
        if (t == 0) red[16] = x;
    }
    __syncthreads();
    float r = red[16];
    __syncthreads();
    return r;
}

// ---------- kA: blocks [0,B): per-batch precompute (k1); blocks [B,2B): allocation ----------
__global__ __launch_bounds__(256) void kA_pre_alloc(
    const void* __restrict__ x,   const void* __restrict__ qy,
    const void* __restrict__ I_w, const void* __restrict__ I_b,
    const void* __restrict__ W1w, const void* __restrict__ W1b,
    const void* __restrict__ W2w, const void* __restrict__ W2b,
    const void* __restrict__ R1w, const void* __restrict__ R1b,
    const void* __restrict__ R2w, const void* __restrict__ R2b,
    const void* __restrict__ rw,  const void* __restrict__ ww,
    const void* __restrict__ us,  const void* __restrict__ fg,
    float* __restrict__ emb_ws, float* __restrict__ v_ws, float* __restrict__ u2_ws,
    float* __restrict__ c1_ws,  float* __restrict__ c2_ws,
    float* __restrict__ alloc_ws, void* __restrict__ dout)
{
    __shared__ unsigned long long sh64[M];   // 16 KB (sort path; aliased as floats in k1 path)
    __shared__ float scan[256];
    const int bf = detect_bf(us);
    const int t = threadIdx.x;

    if (blockIdx.x < B) {
        // ================= k1 precompute path =================
        const int b = blockIdx.x;
        float* fsm  = (float*)sh64;          // 4096 floats available
        float* xs   = fsm;                   // 512
        float* qs   = fsm + 512;             // 512
        float* embs = fsm + 1024;            // 128
        float* wis  = fsm + 1152;            // 64
        float* rqs  = fsm + 1216;            // 64
        float* red  = scan;                  // 256

        for (int i = t; i < IN; i += 256) xs[i] = ldf(x,  (size_t)b*IN + i, bf);
        for (int i = t; i < Qd; i += 256) qs[i] = ldf(qy, (size_t)b*Qd + i, bf);
        __syncthreads();

        // phase 1: emb[t<128] || Rq[t2<64]
        if (t < 128) {
            float acc = 0.f;
            for (int c = 0; c < IN/8; ++c) {
                float m8[8]; ld8(I_w, (size_t)t*IN + c*8, bf, m8);
                #pragma unroll
                for (int j = 0; j < 8; ++j) acc += m8[j] * xs[c*8 + j];
            }
            acc += ldf(I_b, t, bf);
            embs[t] = acc;
            emb_ws[(size_t)b*E + t] = acc;
        } else {
            int t2 = t - 128;
            if (t2 < H) {
                float rv = 0.f;
                for (int c = 0; c < Qd/8; ++c) {
                    float m8[8]; ld8(R1w, (size_t)t2*Qd + c*8, bf, m8);
                    #pragma unroll
                    for (int j = 0; j < 8; ++j) rv += m8[j] * qs[c*8 + j];
                }
                rv += ldf(R1b, t2, bf);
                rqs[t2] = rv;
            }
        }
        __syncthreads();

        // phase 2: Wi[t<64] || u2[t2<128] + c2 partials
        if (t < H) {
            float wv = 0.f;
            for (int c = 0; c < E/8; ++c) {
                float m8[8]; ld8(W1w, (size_t)t*E + c*8, bf, m8);
                #pragma unroll
                for (int j = 0; j < 8; ++j) wv += m8[j] * embs[c*8 + j];
            }
            wv += ldf(W1b, t, bf);
            wis[t] = wv;
        } else if (t >= 128) {
            int t2 = t - 128;
            float uu = 0.f;
            for (int h = 0; h < H; ++h) uu += ldf(R2w, (size_t)h*E + t2, bf) * rqs[h];
            u2_ws[(size_t)b*E + t2] = uu;
            red[t] = (t2 < H) ? rqs[t2] * ldf(R2b, t2, bf) : 0.f;
        }
        __syncthreads();

        // phase 3: v[t<128] + c1 partials
        if (t < 128) {
            float vv = 0.f;
            for (int h = 0; h < H; ++h) vv += ldf(W2w, (size_t)h*E + t, bf) * wis[h];
            v_ws[(size_t)b*E + t] = vv;
            red[t] = (t < H) ? wis[t] * ldf(W2b, t, bf) : 0.f;
        }
        __syncthreads();

        // dual half-reductions: red[0:128) -> c1, red[128:256) -> c2
        for (int off = 64; off > 0; off >>= 1) {
            if (t < off) red[t] += red[t + off];
            if (t >= 128 && t < 128 + off) red[t] += red[t + off];
            __syncthreads();
        }
        if (t == 0)   c1_ws[b] = red[0];
        if (t == 128) c2_ws[b] = red[128];

    } else {
        // ================= allocation path (register bitonic) =================
        const int b = blockIdx.x - B;
        const size_t base = (size_t)b*M + (size_t)t*8;
        float r8[8], w8[8], u8[8], f8[8], nu[8];
        ld8(rw, base, bf, r8); ld8(ww, base, bf, w8);
        ld8(us, base, bf, u8); ld8(fg, base, bf, f8);

        unsigned long long key[8];
        #pragma unroll
        for (int q = 0; q < 8; ++q) {
            float u = 1e-5f + (1.0f - 1e-5f) * u8[q];
            float psi = 1.0f - f8[q] * r8[q];
            u = u + w8[q] - u * w8[q];
            u = u * psi;
            nu[q] = u;
            unsigned fb = __float_as_uint(u);
            fb = (fb & 0x80000000u) ? ~fb : (fb | 0x80000000u);
            key[q] = ((unsigned long long)fb << 32) | (unsigned)(t*8 + q);
        }
        st8(dout, OFF_U + base, bf, nu);          // new_usage output

        // Bitonic sort ascending on uint64 keys, 8 elems/thread (i = t*8+q)
        for (int k = 2; k <= M; k <<= 1) {
            for (int j = k >> 1; j > 0; j >>= 1) {
                if (j >= 512) {
                    __syncthreads();
                    #pragma unroll
                    for (int q = 0; q < 8; ++q) sh64[t*8 + q] = key[q];
                    __syncthreads();
                    const bool up      = (((t << 3) & k) == 0);
                    const bool lower   = (((t << 3) & j) == 0);
                    const bool keepmin = (lower == up);
                    #pragma unroll
                    for (int q = 0; q < 8; ++q) {
                        unsigned long long o = sh64[(t*8 + q) ^ j];
                        bool take = keepmin ? (o < key[q]) : (o > key[q]);
                        if (take) key[q] = o;
                    }
                } else if (j >= 8) {
                    const int d = j >> 3;
                    const bool up      = (((t << 3) & k) == 0);
                    const bool keepmin = (((t & d) == 0) == up);
                    #pragma unroll
                    for (int q = 0; q < 8; ++q) {
                        unsigned long long o = __shfl_xor(key[q], d, 64);
                        bool take = keepmin ? (o < key[q]) : (o > key[q]);
                        if (take) key[q] = o;
                    }
                } else {
                    #pragma unroll
                    for (int q = 0; q < 8; ++q) {
                        if (!(q & j)) {
                            int p = q | j;
                            bool up = ((((t << 3) + q) & k) == 0);
                            unsigned long long a = key[q], c = key[p];
                            bool sw = up ? (a > c) : (a < c);
                            if (sw) { key[q] = c; key[p] = a; }
                        }
                    }
                }
            }
        }

        // extract sorted (u, idx); inclusive cumprod; scatter alloc
        float su[8], lp[8]; int sidx[8];
        #pragma unroll
        for (int q = 0; q < 8; ++q) {
            unsigned fb = (unsigned)(key[q] >> 32);
            fb = (fb & 0x80000000u) ? (fb ^ 0x80000000u) : ~fb;
            su[q]   = __uint_as_float(fb);
            sidx[q] = (int)(key[q] & 0xffffffffu);
        }
        float run = 1.f;
        #pragma unroll
        for (int q = 0; q < 8; ++q) { run *= su[q]; lp[q] = run; }
        scan[t] = run;
        __syncthreads();
        for (int off = 1; off < 256; off <<= 1) {
            float val = scan[t];
            float oth = (t >= off) ? scan[t - off] : 1.0f;
            __syncthreads();
            scan[t] = val * oth;
            __syncthreads();
        }
        float pref = (t > 0) ? scan[t - 1] : 1.0f;
        #pragma unroll
        for (int q = 0; q < 8; ++q)
            alloc_ws[(size_t)b*M + sidx[q]] = (1.0f - su[q]) * (pref * lp[q]);
    }
}

// ---------- kSW: one block per batch. scores into LDS, softmax chain, w/wr out ----------
__global__ __launch_bounds__(1024) void kSW_scores_weights(
    const void* __restrict__ mem, const void* __restrict__ us,
    const float* __restrict__ v_ws, const float* __restrict__ u2_ws,
    const float* __restrict__ c1_ws, const float* __restrict__ c2_ws,
    const float* __restrict__ emb_ws, const float* __restrict__ alloc_ws,
    float* __restrict__ w_ws, float* __restrict__ wr_ws,
    void* __restrict__ dout)
{
    __shared__ float s1s[M];     // 8 KB
    __shared__ float s2s[M];     // 8 KB
    __shared__ float red[17];
    const int bf = detect_bf(us);
    const int b = blockIdx.x, t = threadIdx.x;
    const int l = t & 15, g = t >> 4;        // g in [0,64)

    // ---- scores: s1 = v.mem + c1, s2 = u2.mem (into LDS) ----
    float v8[8], u8[8];
    {
        const float* vb = v_ws  + (size_t)b*E + l*8;
        const float* ub = u2_ws + (size_t)b*E + l*8;
        #pragma unroll
        for (int j = 0; j < 8; ++j) { v8[j] = vb[j]; u8[j] = ub[j]; }
    }
    const float cc1 = c1_ws[b];
    const size_t mbase = (size_t)b*M*E;
    for (int it = 0; it < M/64; ++it) {
        int row = it*64 + g;
        float m8[8]; ld8(mem, mbase + (size_t)row*E + l*8, bf, m8);
        float p1 = 0.f, p2 = 0.f;
        #pragma unroll
        for (int j = 0; j < 8; ++j) { p1 += m8[j]*v8[j]; p2 += m8[j]*u8[j]; }
        #pragma unroll
        for (int mask = 8; mask > 0; mask >>= 1) {
            p1 += __shfl_xor(p1, mask, 16);
            p2 += __shfl_xor(p2, mask, 16);
        }
        if (l == 0) { s1s[row] = p1 + cc1; s2s[row] = p2; }
    }

    // d2 = dot(u2, emb) over E=128 (blk_sum's internal barriers also publish s1s/s2s)
    float dp = (t < E) ? u2_ws[(size_t)b*E + t] * emb_ws[(size_t)b*E + t] : 0.f;
    const float dd = blk_sum(dp, red, t);
    const float cc = c2_ws[b];

    // ---- softmax 1 over s1 -> w ----
    float a0 = s1s[t], a1 = s1s[t + 1024];
    float gmax = blk_max(fmaxf(a0, a1), red, t);
    float e0 = expf(a0 - gmax), e1 = expf(a1 - gmax);
    float inv = 1.0f / blk_sum(e0 + e1, red, t);

    float w0 = 0.5f * (e0*inv + alloc_ws[(size_t)b*M + t]);
    float w1 = 0.5f * (e1*inv + alloc_ws[(size_t)b*M + t + 1024]);
    w_ws[(size_t)b*M + t]        = w0;
    w_ws[(size_t)b*M + t + 1024] = w1;
    st1(dout, OFF_W + (size_t)b*M + t,        bf, w0);
    st1(dout, OFF_W + (size_t)b*M + t + 1024, bf, w1);
    float r0 = s2s[t]        + w0 * dd + cc;
    float r1 = s2s[t + 1024] + w1 * dd + cc;

    // ---- softmax 2 over rs -> wr ----
    gmax = blk_max(fmaxf(r0, r1), red, t);
    e0 = expf(r0 - gmax); e1 = expf(r1 - gmax);
    inv = 1.0f / blk_sum(e0 + e1, red, t);
    float wr0 = e0 * inv, wr1 = e1 * inv;
    wr_ws[(size_t)b*M + t]        = wr0;
    wr_ws[(size_t)b*M + t + 1024] = wr1;
    st1(dout, OFF_WR + (size_t)b*M + t,        bf, wr0);
    st1(dout, OFF_WR + (size_t)b*M + t + 1024, bf, wr1);
}

// ---------- kUO: one block per batch. new_mem stream + pooled + output matvec ----------
__global__ __launch_bounds__(1024) void kUO_update_out(
    const void* __restrict__ mem, const void* __restrict__ us,
    const float* __restrict__ emb_ws,
    const float* __restrict__ w_ws, const float* __restrict__ wr_ws,
    const void* __restrict__ O_w, const void* __restrict__ O_b,
    void* __restrict__ dout)
{
    __shared__ float wsh[M];        // 8 KB
    __shared__ float wrsh[M];       // 8 KB
    __shared__ float pred[16][E];   // 8 KB
    __shared__ float ps[E];
    const int bf = detect_bf(us);
    const int b = blockIdx.x, t = threadIdx.x;
    const int l = t & 15, g = t >> 4;

    wsh [t]        = w_ws [(size_t)b*M + t];
    wsh [t + 1024] = w_ws [(size_t)b*M + t + 1024];
    wrsh[t]        = wr_ws[(size_t)b*M + t];
    wrsh[t + 1024] = wr_ws[(size_t)b*M + t + 1024];
    float e8[8];
    {
        const float* eb = emb_ws + (size_t)b*E + l*8;
        #pragma unroll
        for (int j = 0; j < 8; ++j) e8[j] = eb[j];
    }
    __syncthreads();

    float acc[8] = {0,0,0,0,0,0,0,0};
    const size_t mbase = (size_t)b*M*E;
    for (int it = 0; it < M/64; ++it) {
        int row = it*64 + g;
        size_t off = mbase + (size_t)row*E + l*8;
        float m8[8]; ld8(mem, off, bf, m8);
        const float wv  = wsh[row];
        const float wrv = wrsh[row];
        float n8[8];
        #pragma unroll
        for (int j = 0; j < 8; ++j) {
            n8[j] = m8[j] + wv * e8[j];
            acc[j] += wrv * n8[j];
        }
        st8(dout, OFF_NM + off, bf, n8);          // new_memory output
    }
    // pooled: reduce 4 g-groups within wave, then 16 waves via LDS
    #pragma unroll
    for (int j = 0; j < 8; ++j) {
        acc[j] += __shfl_xor(acc[j], 16, 64);
        acc[j] += __shfl_xor(acc[j], 32, 64);
    }
    const int wid = t >> 6;
    if ((t & 63) < 16) {
        const int l0 = t & 15;
        #pragma unroll
        for (int j = 0; j < 8; ++j) pred[wid][l0*8 + j] = acc[j];
    }
    __syncthreads();
    if (t < E) {
        float s = 0.f;
        #pragma unroll
        for (int w16 = 0; w16 < 16; ++w16) s += pred[w16][t];
        ps[t] = s;
    }
    __syncthreads();

    // output = pooled @ O_w^T + O_b (threads 0..511)
    if (t < OUTd) {
        float a = 0.f;
        for (int c = 0; c < E/8; ++c) {
            float m8[8]; ld8(O_w, (size_t)t*E + c*8, bf, m8);
            #pragma unroll
            for (int j = 0; j < 8; ++j) a += m8[j] * ps[c*8 + j];
        }
        a += ldf(O_b, t, bf);
        st1(dout, OFF_Y + (size_t)b*OUTd + t, bf, a);
    }
}

extern "C" void kernel_launch(void* const* d_in, const int* in_sizes, int n_in,
                              void* d_out, int out_size, void* d_ws, size_t ws_size,
                              hipStream_t stream)
{
    const void* rw  = d_in[0];
    const void* ww  = d_in[1];
    const void* us  = d_in[2];
    const void* fg  = d_in[3];
    const void* x   = d_in[4];
    const void* qy  = d_in[5];
    const void* mem = d_in[6];
    const void* I_w = d_in[7];
    const void* I_b = d_in[8];
    const void* W1w = d_in[9];
    const void* W1b = d_in[10];
    const void* W2w = d_in[11];
    const void* W2b = d_in[12];
    const void* R1w = d_in[13];
    const void* R1b = d_in[14];
    const void* R2w = d_in[15];
    const void* R2b = d_in[16];
    const void* O_w = d_in[17];
    const void* O_b = d_in[18];

    float* fbase   = (float*)d_ws;
    float* emb_ws   = fbase;                          // B*E
    float* v_ws     = emb_ws + (size_t)B*E;           // B*E
    float* u2_ws    = v_ws   + (size_t)B*E;           // B*E
    float* c1_ws    = u2_ws  + (size_t)B*E;           // B
    float* c2_ws    = c1_ws  + B;                     // B
    float* alloc_ws = c2_ws  + B;                     // B*M
    float* w_ws     = alloc_ws + (size_t)B*M;         // B*M
    float* wr_ws    = w_ws     + (size_t)B*M;         // B*M

    kA_pre_alloc<<<2*B, 256, 0, stream>>>(x, qy, I_w, I_b, W1w, W1b, W2w, W2b,
                                          R1w, R1b, R2w, R2b, rw, ww, us, fg,
                                          emb_ws, v_ws, u2_ws, c1_ws, c2_ws,
                                          alloc_ws, d_out);
    kSW_scores_weights<<<B, 1024, 0, stream>>>(mem, us, v_ws, u2_ws, c1_ws, c2_ws,
                                          emb_ws, alloc_ws, w_ws, wr_ws, d_out);
    kUO_update_out<<<B, 1024, 0, stream>>>(mem, us, emb_ws, w_ws, wr_ws,
                                          O_w, O_b, d_out);
}

// Round 4
// 670.879 us; speedup vs baseline: 3.9107x; 1.0210x over previous
//
#include <hip/hip_runtime.h>
#include <hip/hip_bf16.h>

// Problem sizes (fixed)
constexpr int B   = 256;
constexpr int M   = 2048;
constexpr int E   = 128;
constexpr int IN  = 512;
constexpr int Qd  = 512;
constexpr int OUTd= 512;
constexpr int H   = 64;

// Output element offsets (same element layout for bf16 or f32 outputs)
constexpr size_t OFF_WR = 0;
constexpr size_t OFF_W  = (size_t)B*M;
constexpr size_t OFF_U  = (size_t)2*B*M;
constexpr size_t OFF_Y  = (size_t)3*B*M;
constexpr size_t OFF_NM = OFF_Y + (size_t)B*OUTd;

// ---------- bf16 helpers ----------
__device__ __forceinline__ float bf2f(unsigned short u) {
    union { unsigned int i; float f; } v; v.i = ((unsigned int)u) << 16; return v.f;
}
__device__ __forceinline__ unsigned short f2bf(float f) {
    unsigned int x = __float_as_uint(f);
    unsigned int r = (x + 0x7fffu + ((x >> 16) & 1u)) >> 16;   // RNE
    return (unsigned short)r;
}
__device__ __forceinline__ void unpack8(uint4 d, float* o) {
    o[0]=bf2f(d.x & 0xffff); o[1]=bf2f(d.x >> 16);
    o[2]=bf2f(d.y & 0xffff); o[3]=bf2f(d.y >> 16);
    o[4]=bf2f(d.z & 0xffff); o[5]=bf2f(d.z >> 16);
    o[6]=bf2f(d.w & 0xffff); o[7]=bf2f(d.w >> 16);
}
__device__ __forceinline__ uint4 pack8(const float* f) {
    uint4 d;
    d.x = (unsigned)f2bf(f[0]) | ((unsigned)f2bf(f[1]) << 16);
    d.y = (unsigned)f2bf(f[2]) | ((unsigned)f2bf(f[3]) << 16);
    d.z = (unsigned)f2bf(f[4]) | ((unsigned)f2bf(f[5]) << 16);
    d.w = (unsigned)f2bf(f[6]) | ((unsigned)f2bf(f[7]) << 16);
    return d;
}

// ---------- dual-dtype load/store (bf = 1 -> bf16, 0 -> f32); wave-uniform branch ----------
__device__ __forceinline__ float ldf(const void* p, size_t i, int bf) {
    return bf ? bf2f(((const unsigned short*)p)[i]) : ((const float*)p)[i];
}
__device__ __forceinline__ void ld8(const void* p, size_t i, int bf, float* o) {
    if (bf) {
        uint4 d = *(const uint4*)((const unsigned short*)p + i);
        unpack8(d, o);
    } else {
        const float4* q = (const float4*)((const float*)p + i);
        float4 a = q[0], c = q[1];
        o[0]=a.x; o[1]=a.y; o[2]=a.z; o[3]=a.w;
        o[4]=c.x; o[5]=c.y; o[6]=c.z; o[7]=c.w;
    }
}
__device__ __forceinline__ void st1(void* p, size_t i, int bf, float v) {
    if (bf) ((unsigned short*)p)[i] = f2bf(v);
    else    ((float*)p)[i] = v;
}
__device__ __forceinline__ void st8(void* p, size_t i, int bf, const float* v) {
    if (bf) {
        *(uint4*)((unsigned short*)p + i) = pack8(v);
    } else {
        float4 a, c;
        a.x=v[0]; a.y=v[1]; a.z=v[2]; a.w=v[3];
        c.x=v[4]; c.y=v[5]; c.z=v[6]; c.w=v[7];
        float4* q = (float4*)((float*)p + i);
        q[0]=a; q[1]=c;
    }
}

// ---------- inline dtype detector (per-wave ballot over first 512 u16 of usage) ----------
__device__ __forceinline__ int detect_bf(const void* usage) {
    const int lane = threadIdx.x & 63;
    uint4 d = ((const uint4*)usage)[lane];   // 8 u16 entries
    float o[8]; unpack8(d, o);
    bool ok = true;
    #pragma unroll
    for (int j = 0; j < 8; ++j) ok = ok && (o[j] >= 0.0f && o[j] <= 1.0f);
    unsigned long long m = __ballot(ok);
    return (__popcll(m) >= 32) ? 1 : 0;
}

// ---------- block reductions for 256 threads (4 waves): shfl + 4-slot LDS ----------
__device__ __forceinline__ float bmax4(float v, float* r4, int t) {
    #pragma unroll
    for (int m = 1; m < 64; m <<= 1) v = fmaxf(v, __shfl_xor(v, m, 64));
    __syncthreads();
    if ((t & 63) == 0) r4[t >> 6] = v;
    __syncthreads();
    return fmaxf(fmaxf(r4[0], r4[1]), fmaxf(r4[2], r4[3]));
}
__device__ __forceinline__ float bsum4(float v, float* r4, int t) {
    #pragma unroll
    for (int m = 1; m < 64; m <<= 1) v += __shfl_xor(v, m, 64);
    __syncthreads();
    if ((t & 63) == 0) r4[t >> 6] = v;
    __syncthreads();
    return (r4[0] + r4[1]) + (r4[2] + r4[3]);
}

// ---------- kA: blocks [0,B): per-batch precompute (k1+d2); blocks [B,2B): allocation ----------
__global__ __launch_bounds__(256) void kA_pre_alloc(
    const void* __restrict__ x,   const void* __restrict__ qy,
    const void* __restrict__ I_w, const void* __restrict__ I_b,
    const void* __restrict__ W1w, const void* __restrict__ W1b,
    const void* __restrict__ W2w, const void* __restrict__ W2b,
    const void* __restrict__ R1w, const void* __restrict__ R1b,
    const void* __restrict__ R2w, const void* __restrict__ R2b,
    const void* __restrict__ rw,  const void* __restrict__ ww,
    const void* __restrict__ us,  const void* __restrict__ fg,
    float* __restrict__ emb_ws, float* __restrict__ v_ws, float* __restrict__ u2_ws,
    float* __restrict__ c1_ws,  float* __restrict__ c2_ws, float* __restrict__ d2_ws,
    float* __restrict__ alloc_ws, void* __restrict__ dout)
{
    __shared__ unsigned long long sh64[M];   // 16 KB (sort path; aliased as floats in k1 path)
    __shared__ float scan[256];
    const int bf = detect_bf(us);
    const int t = threadIdx.x;

    if (blockIdx.x < B) {
        // ================= k1 precompute path =================
        const int b = blockIdx.x;
        float* fsm  = (float*)sh64;          // 4096 floats available
        float* xs   = fsm;                   // 512
        float* qs   = fsm + 512;             // 512
        float* embs = fsm + 1024;            // 128
        float* wis  = fsm + 1152;            // 64
        float* rqs  = fsm + 1216;            // 64
        float* red  = scan;                  // 256
        float uu = 0.f;                      // u2 value held by threads >=128

        for (int i = t; i < IN; i += 256) xs[i] = ldf(x,  (size_t)b*IN + i, bf);
        for (int i = t; i < Qd; i += 256) qs[i] = ldf(qy, (size_t)b*Qd + i, bf);
        __syncthreads();

        // phase 1: emb[t<128] || Rq[t2<64]
        if (t < 128) {
            float acc = 0.f;
            for (int c = 0; c < IN/8; ++c) {
                float m8[8]; ld8(I_w, (size_t)t*IN + c*8, bf, m8);
                #pragma unroll
                for (int j = 0; j < 8; ++j) acc += m8[j] * xs[c*8 + j];
            }
            acc += ldf(I_b, t, bf);
            embs[t] = acc;
            emb_ws[(size_t)b*E + t] = acc;
        } else {
            int t2 = t - 128;
            if (t2 < H) {
                float rv = 0.f;
                for (int c = 0; c < Qd/8; ++c) {
                    float m8[8]; ld8(R1w, (size_t)t2*Qd + c*8, bf, m8);
                    #pragma unroll
                    for (int j = 0; j < 8; ++j) rv += m8[j] * qs[c*8 + j];
                }
                rv += ldf(R1b, t2, bf);
                rqs[t2] = rv;
            }
        }
        __syncthreads();

        // phase 2: Wi[t<64] || u2[t2<128] + c2 partials
        if (t < H) {
            float wv = 0.f;
            for (int c = 0; c < E/8; ++c) {
                float m8[8]; ld8(W1w, (size_t)t*E + c*8, bf, m8);
                #pragma unroll
                for (int j = 0; j < 8; ++j) wv += m8[j] * embs[c*8 + j];
            }
            wv += ldf(W1b, t, bf);
            wis[t] = wv;
        } else if (t >= 128) {
            int t2 = t - 128;
            for (int h = 0; h < H; ++h) uu += ldf(R2w, (size_t)h*E + t2, bf) * rqs[h];
            u2_ws[(size_t)b*E + t2] = uu;
            red[t] = (t2 < H) ? rqs[t2] * ldf(R2b, t2, bf) : 0.f;
        }
        __syncthreads();

        // phase 3: v[t<128] + c1 partials
        if (t < 128) {
            float vv = 0.f;
            for (int h = 0; h < H; ++h) vv += ldf(W2w, (size_t)h*E + t, bf) * wis[h];
            v_ws[(size_t)b*E + t] = vv;
            red[t] = (t < H) ? wis[t] * ldf(W2b, t, bf) : 0.f;
        }
        __syncthreads();

        // dual half-reductions: red[0:128) -> c1, red[128:256) -> c2
        for (int off = 64; off > 0; off >>= 1) {
            if (t < off) red[t] += red[t + off];
            if (t >= 128 && t < 128 + off) red[t] += red[t + off];
            __syncthreads();
        }
        if (t == 0)   c1_ws[b] = red[0];
        if (t == 128) c2_ws[b] = red[128];
        __syncthreads();

        // d2 = dot(u2, emb): upper-half reduction
        red[t] = (t >= 128) ? uu * embs[t - 128] : 0.f;
        __syncthreads();
        for (int off = 64; off > 0; off >>= 1) {
            if (t >= 128 && t < 128 + off) red[t] += red[t + off];
            __syncthreads();
        }
        if (t == 128) d2_ws[b] = red[128];

    } else {
        // ================= allocation path (register bitonic) =================
        const int b = blockIdx.x - B;
        const size_t base = (size_t)b*M + (size_t)t*8;
        float r8[8], w8[8], u8[8], f8[8], nu[8];
        ld8(rw, base, bf, r8); ld8(ww, base, bf, w8);
        ld8(us, base, bf, u8); ld8(fg, base, bf, f8);

        unsigned long long key[8];
        #pragma unroll
        for (int q = 0; q < 8; ++q) {
            float u = 1e-5f + (1.0f - 1e-5f) * u8[q];
            float psi = 1.0f - f8[q] * r8[q];
            u = u + w8[q] - u * w8[q];
            u = u * psi;
            nu[q] = u;
            unsigned fb = __float_as_uint(u);
            fb = (fb & 0x80000000u) ? ~fb : (fb | 0x80000000u);
            key[q] = ((unsigned long long)fb << 32) | (unsigned)(t*8 + q);
        }
        st8(dout, OFF_U + base, bf, nu);          // new_usage output

        // Bitonic sort ascending on uint64 keys, 8 elems/thread (i = t*8+q)
        for (int k = 2; k <= M; k <<= 1) {
            for (int j = k >> 1; j > 0; j >>= 1) {
                if (j >= 512) {
                    __syncthreads();
                    #pragma unroll
                    for (int q = 0; q < 8; ++q) sh64[t*8 + q] = key[q];
                    __syncthreads();
                    const bool up      = (((t << 3) & k) == 0);
                    const bool lower   = (((t << 3) & j) == 0);
                    const bool keepmin = (lower == up);
                    #pragma unroll
                    for (int q = 0; q < 8; ++q) {
                        unsigned long long o = sh64[(t*8 + q) ^ j];
                        bool take = keepmin ? (o < key[q]) : (o > key[q]);
                        if (take) key[q] = o;
                    }
                } else if (j >= 8) {
                    const int d = j >> 3;
                    const bool up      = (((t << 3) & k) == 0);
                    const bool keepmin = (((t & d) == 0) == up);
                    #pragma unroll
                    for (int q = 0; q < 8; ++q) {
                        unsigned long long o = __shfl_xor(key[q], d, 64);
                        bool take = keepmin ? (o < key[q]) : (o > key[q]);
                        if (take) key[q] = o;
                    }
                } else {
                    #pragma unroll
                    for (int q = 0; q < 8; ++q) {
                        if (!(q & j)) {
                            int p = q | j;
                            bool up = ((((t << 3) + q) & k) == 0);
                            unsigned long long a = key[q], c = key[p];
                            bool sw = up ? (a > c) : (a < c);
                            if (sw) { key[q] = c; key[p] = a; }
                        }
                    }
                }
            }
        }

        // extract sorted (u, idx); inclusive cumprod; scatter alloc
        float su[8], lp[8]; int sidx[8];
        #pragma unroll
        for (int q = 0; q < 8; ++q) {
            unsigned fb = (unsigned)(key[q] >> 32);
            fb = (fb & 0x80000000u) ? (fb ^ 0x80000000u) : ~fb;
            su[q]   = __uint_as_float(fb);
            sidx[q] = (int)(key[q] & 0xffffffffu);
        }
        float run = 1.f;
        #pragma unroll
        for (int q = 0; q < 8; ++q) { run *= su[q]; lp[q] = run; }
        scan[t] = run;
        __syncthreads();
        for (int off = 1; off < 256; off <<= 1) {
            float val = scan[t];
            float oth = (t >= off) ? scan[t - off] : 1.0f;
            __syncthreads();
            scan[t] = val * oth;
            __syncthreads();
        }
        float pref = (t > 0) ? scan[t - 1] : 1.0f;
        #pragma unroll
        for (int q = 0; q < 8; ++q)
            alloc_ws[(size_t)b*M + sidx[q]] = (1.0f - su[q]) * (pref * lp[q]);
    }
}

// ---------- kS: scores per (b,chunk), 4096 blocks x 256 thr: s1 = v.mem + c1, s2 = u2.mem ----------
__global__ __launch_bounds__(256) void kS_scores(
    const void* __restrict__ mem, const void* __restrict__ us,
    const float* __restrict__ v_ws, const float* __restrict__ u2_ws,
    const float* __restrict__ c1_ws,
    float* __restrict__ s1, float* __restrict__ s2)
{
    const int bf = detect_bf(us);
    const int blk = blockIdx.x;
    const int b = blk >> 4, chunk = blk & 15;
    const int t = threadIdx.x, l = t & 15, g = t >> 4;
    float v8[8], u8[8];
    {
        const float* vb = v_ws  + (size_t)b*E + l*8;
        const float* ub = u2_ws + (size_t)b*E + l*8;
        #pragma unroll
        for (int j = 0; j < 8; ++j) { v8[j] = vb[j]; u8[j] = ub[j]; }
    }
    const float cc1 = c1_ws[b];
    const size_t mbase = (size_t)b*M*E;
    const int row0 = chunk*128 + g;
    for (int it = 0; it < 8; ++it) {
        int row = row0 + it*16;
        float m8[8]; ld8(mem, mbase + (size_t)row*E + l*8, bf, m8);
        float p1 = 0.f, p2 = 0.f;
        #pragma unroll
        for (int j = 0; j < 8; ++j) { p1 += m8[j]*v8[j]; p2 += m8[j]*u8[j]; }
        #pragma unroll
        for (int mask = 8; mask > 0; mask >>= 1) {
            p1 += __shfl_xor(p1, mask, 16);
            p2 += __shfl_xor(p2, mask, 16);
        }
        if (l == 0) {
            s1[(size_t)b*M + row] = p1 + cc1;
            s2[(size_t)b*M + row] = p2;
        }
    }
}

// ---------- kU: per (b,chunk) reversed. Redundant softmax head -> w,wr in LDS;
//              chunk-0 writes w/wr outputs; stream new_mem + pooled partials ----------
__global__ __launch_bounds__(256) void kU_update(
    const void* __restrict__ mem, const void* __restrict__ us,
    const float* __restrict__ emb_ws, const float* __restrict__ alloc_ws,
    const float* __restrict__ s1, const float* __restrict__ s2,
    const float* __restrict__ c2_ws, const float* __restrict__ d2_ws,
    float* __restrict__ pooled_p, void* __restrict__ dout)
{
    __shared__ float wsh[M];      // 8 KB
    __shared__ float wrsh[M];     // 8 KB
    __shared__ float pw[4][E];    // 2 KB
    __shared__ float r4[4];
    const int bf = detect_bf(us);
    const int rblk = (B*16 - 1) - (int)blockIdx.x;   // reversed vs kS for L3 reuse
    const int b = rblk >> 4, chunk = rblk & 15;
    const int t = threadIdx.x, l = t & 15, g = t >> 4;

    // ---- softmax head over full batch (redundant per chunk block; L2/L3-hot reads) ----
    const float* s1b = s1 + (size_t)b*M;
    const float* s2b = s2 + (size_t)b*M;
    float sv[8];
    float lmax = -3.4e38f;
    #pragma unroll
    for (int s = 0; s < 8; ++s) { sv[s] = s1b[s*256 + t]; lmax = fmaxf(lmax, sv[s]); }
    float gmax = bmax4(lmax, r4, t);
    float lsum = 0.f;
    #pragma unroll
    for (int s = 0; s < 8; ++s) { float e = expf(sv[s] - gmax); sv[s] = e; lsum += e; }
    float inv = 1.0f / bsum4(lsum, r4, t);

    const float dd = d2_ws[b], cc = c2_ws[b];
    float rs[8];
    #pragma unroll
    for (int s = 0; s < 8; ++s) {
        int m = s*256 + t;
        float wv = 0.5f * (sv[s] * inv + alloc_ws[(size_t)b*M + m]);
        wsh[m] = wv;
        rs[s] = s2b[m] + wv * dd + cc;
        if (chunk == 0) st1(dout, OFF_W + (size_t)b*M + m, bf, wv);
    }

    lmax = -3.4e38f;
    #pragma unroll
    for (int s = 0; s < 8; ++s) lmax = fmaxf(lmax, rs[s]);
    gmax = bmax4(lmax, r4, t);
    lsum = 0.f;
    #pragma unroll
    for (int s = 0; s < 8; ++s) { float e = expf(rs[s] - gmax); rs[s] = e; lsum += e; }
    float inv2 = 1.0f / bsum4(lsum, r4, t);
    #pragma unroll
    for (int s = 0; s < 8; ++s) {
        int m = s*256 + t;
        float wrv = rs[s] * inv2;
        wrsh[m] = wrv;
        if (chunk == 0) st1(dout, OFF_WR + (size_t)b*M + m, bf, wrv);
    }
    __syncthreads();   // publish wsh/wrsh

    // ---- stream: new_mem = mem + w*emb; pooled partial ----
    float e8[8];
    {
        const float* eb = emb_ws + (size_t)b*E + l*8;
        #pragma unroll
        for (int j = 0; j < 8; ++j) e8[j] = eb[j];
    }
    float acc[8] = {0,0,0,0,0,0,0,0};
    const size_t mbase = (size_t)b*M*E;
    const int row0 = chunk*128 + g;
    for (int it = 0; it < 8; ++it) {
        int row = row0 + it*16;
        size_t off = mbase + (size_t)row*E + l*8;
        float m8[8]; ld8(mem, off, bf, m8);
        const float wv  = wsh[row];
        const float wrv = wrsh[row];
        float n8[8];
        #pragma unroll
        for (int j = 0; j < 8; ++j) {
            n8[j] = m8[j] + wv * e8[j];
            acc[j] += wrv * n8[j];
        }
        st8(dout, OFF_NM + off, bf, n8);          // new_memory output
    }
    // reduce over the 16 g-groups: 4 in-wave via shfl, 4 waves via LDS
    #pragma unroll
    for (int j = 0; j < 8; ++j) {
        acc[j] += __shfl_xor(acc[j], 16, 64);
        acc[j] += __shfl_xor(acc[j], 32, 64);
    }
    const int wid = t >> 6;
    if ((t & 63) < 16) {
        const int l0 = t & 15;
        #pragma unroll
        for (int j = 0; j < 8; ++j) pw[wid][l0*8 + j] = acc[j];
    }
    __syncthreads();
    if (t < E)
        pooled_p[((size_t)b*16 + chunk)*E + t] = pw[0][t] + pw[1][t] + pw[2][t] + pw[3][t];
}

// ---------- kO: per batch: pooled = sum chunks; output = pooled @ O_w^T + O_b ----------
__global__ __launch_bounds__(512) void kO_out(
    const float* __restrict__ pooled_p,
    const void* __restrict__ O_w, const void* __restrict__ O_b,
    const void* __restrict__ us, void* __restrict__ dout)
{
    __shared__ float ps[E];
    const int bf = detect_bf(us);
    const int b = blockIdx.x, t = threadIdx.x;
    if (t < E) {
        float s = 0.f;
        #pragma unroll
        for (int c = 0; c < 16; ++c) s += pooled_p[((size_t)b*16 + c)*E + t];
        ps[t] = s;
    }
    __syncthreads();
    float a = 0.f;
    for (int c = 0; c < E/8; ++c) {
        float m8[8]; ld8(O_w, (size_t)t*E + c*8, bf, m8);
        #pragma unroll
        for (int j = 0; j < 8; ++j) a += m8[j] * ps[c*8 + j];
    }
    a += ldf(O_b, t, bf);
    st1(dout, OFF_Y + (size_t)b*OUTd + t, bf, a);
}

extern "C" void kernel_launch(void* const* d_in, const int* in_sizes, int n_in,
                              void* d_out, int out_size, void* d_ws, size_t ws_size,
                              hipStream_t stream)
{
    const void* rw  = d_in[0];
    const void* ww  = d_in[1];
    const void* us  = d_in[2];
    const void* fg  = d_in[3];
    const void* x   = d_in[4];
    const void* qy  = d_in[5];
    const void* mem = d_in[6];
    const void* I_w = d_in[7];
    const void* I_b = d_in[8];
    const void* W1w = d_in[9];
    const void* W1b = d_in[10];
    const void* W2w = d_in[11];
    const void* W2b = d_in[12];
    const void* R1w = d_in[13];
    const void* R1b = d_in[14];
    const void* R2w = d_in[15];
    const void* R2b = d_in[16];
    const void* O_w = d_in[17];
    const void* O_b = d_in[18];

    float* fbase    = (float*)d_ws;
    float* emb_ws   = fbase;                          // B*E
    float* v_ws     = emb_ws + (size_t)B*E;           // B*E
    float* u2_ws    = v_ws   + (size_t)B*E;           // B*E
    float* c1_ws    = u2_ws  + (size_t)B*E;           // B
    float* c2_ws    = c1_ws  + B;                     // B
    float* d2_ws    = c2_ws  + B;                     // B
    float* alloc_ws = d2_ws  + B;                     // B*M
    float* s1_ws    = alloc_ws + (size_t)B*M;         // B*M
    float* s2_ws    = s1_ws    + (size_t)B*M;         // B*M
    float* pooled_p = s2_ws    + (size_t)B*M;         // B*16*E == B*M

    kA_pre_alloc<<<2*B, 256, 0, stream>>>(x, qy, I_w, I_b, W1w, W1b, W2w, W2b,
                                          R1w, R1b, R2w, R2b, rw, ww, us, fg,
                                          emb_ws, v_ws, u2_ws, c1_ws, c2_ws, d2_ws,
                                          alloc_ws, d_out);
    kS_scores<<<B*16, 256, 0, stream>>>(mem, us, v_ws, u2_ws, c1_ws, s1_ws, s2_ws);
    kU_update<<<B*16, 256, 0, stream>>>(mem, us, emb_ws, alloc_ws, s1_ws, s2_ws,
                                        c2_ws, d2_ws, pooled_p, d_out);
    kO_out   <<<B,    512, 0, stream>>>(pooled_p, O_w, O_b, us, d_out);
}

// Round 5
// 625.135 us; speedup vs baseline: 4.1968x; 1.0732x over previous
//
#include <hip/hip_runtime.h>
#include <hip/hip_bf16.h>

// Problem sizes (fixed)
constexpr int B   = 256;
constexpr int M   = 2048;
constexpr int E   = 128;
constexpr int IN  = 512;
constexpr int Qd  = 512;
constexpr int OUTd= 512;
constexpr int H   = 64;

// Output element offsets (same element layout for bf16 or f32 outputs)
constexpr size_t OFF_WR = 0;
constexpr size_t OFF_W  = (size_t)B*M;
constexpr size_t OFF_U  = (size_t)2*B*M;
constexpr size_t OFF_Y  = (size_t)3*B*M;
constexpr size_t OFF_NM = OFF_Y + (size_t)B*OUTd;

// ---------- bf16 helpers ----------
__device__ __forceinline__ float bf2f(unsigned short u) {
    union { unsigned int i; float f; } v; v.i = ((unsigned int)u) << 16; return v.f;
}
__device__ __forceinline__ unsigned short f2bf(float f) {
    unsigned int x = __float_as_uint(f);
    unsigned int r = (x + 0x7fffu + ((x >> 16) & 1u)) >> 16;   // RNE
    return (unsigned short)r;
}
__device__ __forceinline__ void unpack8(uint4 d, float* o) {
    o[0]=bf2f(d.x & 0xffff); o[1]=bf2f(d.x >> 16);
    o[2]=bf2f(d.y & 0xffff); o[3]=bf2f(d.y >> 16);
    o[4]=bf2f(d.z & 0xffff); o[5]=bf2f(d.z >> 16);
    o[6]=bf2f(d.w & 0xffff); o[7]=bf2f(d.w >> 16);
}
__device__ __forceinline__ uint4 pack8(const float* f) {
    uint4 d;
    d.x = (unsigned)f2bf(f[0]) | ((unsigned)f2bf(f[1]) << 16);
    d.y = (unsigned)f2bf(f[2]) | ((unsigned)f2bf(f[3]) << 16);
    d.z = (unsigned)f2bf(f[4]) | ((unsigned)f2bf(f[5]) << 16);
    d.w = (unsigned)f2bf(f[6]) | ((unsigned)f2bf(f[7]) << 16);
    return d;
}

// ---------- dual-dtype load/store (bf = 1 -> bf16, 0 -> f32); wave-uniform branch ----------
__device__ __forceinline__ float ldf(const void* p, size_t i, int bf) {
    return bf ? bf2f(((const unsigned short*)p)[i]) : ((const float*)p)[i];
}
__device__ __forceinline__ void ld8(const void* p, size_t i, int bf, float* o) {
    if (bf) {
        uint4 d = *(const uint4*)((const unsigned short*)p + i);
        unpack8(d, o);
    } else {
        const float4* q = (const float4*)((const float*)p + i);
        float4 a = q[0], c = q[1];
        o[0]=a.x; o[1]=a.y; o[2]=a.z; o[3]=a.w;
        o[4]=c.x; o[5]=c.y; o[6]=c.z; o[7]=c.w;
    }
}
__device__ __forceinline__ void st1(void* p, size_t i, int bf, float v) {
    if (bf) ((unsigned short*)p)[i] = f2bf(v);
    else    ((float*)p)[i] = v;
}
__device__ __forceinline__ void st8(void* p, size_t i, int bf, const float* v) {
    if (bf) {
        *(uint4*)((unsigned short*)p + i) = pack8(v);
    } else {
        float4 a, c;
        a.x=v[0]; a.y=v[1]; a.z=v[2]; a.w=v[3];
        c.x=v[4]; c.y=v[5]; c.z=v[6]; c.w=v[7];
        float4* q = (float4*)((float*)p + i);
        q[0]=a; q[1]=c;
    }
}

// ---------- inline dtype detector (per-wave ballot over first 512 u16 of usage) ----------
__device__ __forceinline__ int detect_bf(const void* usage) {
    const int lane = threadIdx.x & 63;
    uint4 d = ((const uint4*)usage)[lane];   // 8 u16 entries
    float o[8]; unpack8(d, o);
    bool ok = true;
    #pragma unroll
    for (int j = 0; j < 8; ++j) ok = ok && (o[j] >= 0.0f && o[j] <= 1.0f);
    unsigned long long m = __ballot(ok);
    return (__popcll(m) >= 32) ? 1 : 0;
}

// ---------- block reductions for 256 threads (4 waves): shfl + 4-slot LDS ----------
__device__ __forceinline__ float bmax4(float v, float* r4, int t) {
    #pragma unroll
    for (int m = 1; m < 64; m <<= 1) v = fmaxf(v, __shfl_xor(v, m, 64));
    __syncthreads();
    if ((t & 63) == 0) r4[t >> 6] = v;
    __syncthreads();
    return fmaxf(fmaxf(r4[0], r4[1]), fmaxf(r4[2], r4[3]));
}
__device__ __forceinline__ float bsum4(float v, float* r4, int t) {
    #pragma unroll
    for (int m = 1; m < 64; m <<= 1) v += __shfl_xor(v, m, 64);
    __syncthreads();
    if ((t & 63) == 0) r4[t >> 6] = v;
    __syncthreads();
    return (r4[0] + r4[1]) + (r4[2] + r4[3]);
}

// ---------- k1: per-batch small precompute (+d2), two independent chains on thread halves ----------
__global__ __launch_bounds__(256) void k1_pre(
    const void* __restrict__ x,   const void* __restrict__ qy,
    const void* __restrict__ I_w, const void* __restrict__ I_b,
    const void* __restrict__ W1w, const void* __restrict__ W1b,
    const void* __restrict__ W2w, const void* __restrict__ W2b,
    const void* __restrict__ R1w, const void* __restrict__ R1b,
    const void* __restrict__ R2w, const void* __restrict__ R2b,
    const void* __restrict__ us,
    float* __restrict__ emb_ws, float* __restrict__ v_ws, float* __restrict__ u2_ws,
    float* __restrict__ c1_ws,  float* __restrict__ c2_ws, float* __restrict__ d2_ws)
{
    const int bf = detect_bf(us);
    __shared__ float xs[IN], qs[Qd], embs[E], wis[H], rqs[H], red[256];
    const int b = blockIdx.x, t = threadIdx.x;
    float uu = 0.f;                      // u2 value held by threads >=128

    for (int i = t; i < IN; i += 256) xs[i] = ldf(x,  (size_t)b*IN + i, bf);
    for (int i = t; i < Qd; i += 256) qs[i] = ldf(qy, (size_t)b*Qd + i, bf);
    __syncthreads();

    // phase 1: emb[t<128] || Rq[t2<64]
    if (t < 128) {
        float acc = 0.f;
        for (int c = 0; c < IN/8; ++c) {
            float m8[8]; ld8(I_w, (size_t)t*IN + c*8, bf, m8);
            #pragma unroll
            for (int j = 0; j < 8; ++j) acc += m8[j] * xs[c*8 + j];
        }
        acc += ldf(I_b, t, bf);
        embs[t] = acc;
        emb_ws[(size_t)b*E + t] = acc;
    } else {
        int t2 = t - 128;
        if (t2 < H) {
            float rv = 0.f;
            for (int c = 0; c < Qd/8; ++c) {
                float m8[8]; ld8(R1w, (size_t)t2*Qd + c*8, bf, m8);
                #pragma unroll
                for (int j = 0; j < 8; ++j) rv += m8[j] * qs[c*8 + j];
            }
            rv += ldf(R1b, t2, bf);
            rqs[t2] = rv;
        }
    }
    __syncthreads();

    // phase 2: Wi[t<64] || u2[t2<128] + c2 partials
    if (t < H) {
        float wv = 0.f;
        for (int c = 0; c < E/8; ++c) {
            float m8[8]; ld8(W1w, (size_t)t*E + c*8, bf, m8);
            #pragma unroll
            for (int j = 0; j < 8; ++j) wv += m8[j] * embs[c*8 + j];
        }
        wv += ldf(W1b, t, bf);
        wis[t] = wv;
    } else if (t >= 128) {
        int t2 = t - 128;
        for (int h = 0; h < H; ++h) uu += ldf(R2w, (size_t)h*E + t2, bf) * rqs[h];
        u2_ws[(size_t)b*E + t2] = uu;
        red[t] = (t2 < H) ? rqs[t2] * ldf(R2b, t2, bf) : 0.f;
    }
    __syncthreads();

    // phase 3: v[t<128] + c1 partials
    if (t < 128) {
        float vv = 0.f;
        for (int h = 0; h < H; ++h) vv += ldf(W2w, (size_t)h*E + t, bf) * wis[h];
        v_ws[(size_t)b*E + t] = vv;
        red[t] = (t < H) ? wis[t] * ldf(W2b, t, bf) : 0.f;
    }
    __syncthreads();

    // dual half-reductions: red[0:128) -> c1, red[128:256) -> c2
    for (int off = 64; off > 0; off >>= 1) {
        if (t < off) red[t] += red[t + off];
        if (t >= 128 && t < 128 + off) red[t] += red[t + off];
        __syncthreads();
    }
    if (t == 0)   c1_ws[b] = red[0];
    if (t == 128) c2_ws[b] = red[128];
    __syncthreads();

    // d2 = dot(u2, emb): upper-half reduction
    red[t] = (t >= 128) ? uu * embs[t - 128] : 0.f;
    __syncthreads();
    for (int off = 64; off > 0; off >>= 1) {
        if (t >= 128 && t < 128 + off) red[t] += red[t + off];
        __syncthreads();
    }
    if (t == 128) d2_ws[b] = red[128];
}

// ---------- kB: blocks [0,B): allocation (register bitonic); blocks [B,B+16B): scores ----------
__global__ __launch_bounds__(256) void kB_alloc_scores(
    const void* __restrict__ rw, const void* __restrict__ ww,
    const void* __restrict__ us, const void* __restrict__ fg,
    const void* __restrict__ mem,
    const float* __restrict__ v_ws, const float* __restrict__ u2_ws,
    const float* __restrict__ c1_ws,
    float* __restrict__ alloc_ws, float* __restrict__ s1, float* __restrict__ s2,
    void* __restrict__ dout)
{
    __shared__ unsigned long long sh64[M];   // 16 KB, sort path only
    __shared__ float scan[256];
    const int bf = detect_bf(us);
    const int t = threadIdx.x;

    if (blockIdx.x < B) {
        // ================= allocation path =================
        const int b = blockIdx.x;
        const size_t base = (size_t)b*M + (size_t)t*8;
        float r8[8], w8[8], u8[8], f8[8], nu[8];
        ld8(rw, base, bf, r8); ld8(ww, base, bf, w8);
        ld8(us, base, bf, u8); ld8(fg, base, bf, f8);

        unsigned long long key[8];
        #pragma unroll
        for (int q = 0; q < 8; ++q) {
            float u = 1e-5f + (1.0f - 1e-5f) * u8[q];
            float psi = 1.0f - f8[q] * r8[q];
            u = u + w8[q] - u * w8[q];
            u = u * psi;
            nu[q] = u;
            unsigned fb = __float_as_uint(u);
            fb = (fb & 0x80000000u) ? ~fb : (fb | 0x80000000u);
            key[q] = ((unsigned long long)fb << 32) | (unsigned)(t*8 + q);
        }
        st8(dout, OFF_U + base, bf, nu);          // new_usage output

        // Bitonic sort ascending on uint64 keys, 8 elems/thread (i = t*8+q)
        for (int k = 2; k <= M; k <<= 1) {
            for (int j = k >> 1; j > 0; j >>= 1) {
                if (j >= 512) {
                    __syncthreads();
                    #pragma unroll
                    for (int q = 0; q < 8; ++q) sh64[t*8 + q] = key[q];
                    __syncthreads();
                    const bool up      = (((t << 3) & k) == 0);
                    const bool lower   = (((t << 3) & j) == 0);
                    const bool keepmin = (lower == up);
                    #pragma unroll
                    for (int q = 0; q < 8; ++q) {
                        unsigned long long o = sh64[(t*8 + q) ^ j];
                        bool take = keepmin ? (o < key[q]) : (o > key[q]);
                        if (take) key[q] = o;
                    }
                } else if (j >= 8) {
                    const int d = j >> 3;
                    const bool up      = (((t << 3) & k) == 0);
                    const bool keepmin = (((t & d) == 0) == up);
                    #pragma unroll
                    for (int q = 0; q < 8; ++q) {
                        unsigned long long o = __shfl_xor(key[q], d, 64);
                        bool take = keepmin ? (o < key[q]) : (o > key[q]);
                        if (take) key[q] = o;
                    }
                } else {
                    #pragma unroll
                    for (int q = 0; q < 8; ++q) {
                        if (!(q & j)) {
                            int p = q | j;
                            bool up = ((((t << 3) + q) & k) == 0);
                            unsigned long long a = key[q], c = key[p];
                            bool sw = up ? (a > c) : (a < c);
                            if (sw) { key[q] = c; key[p] = a; }
                        }
                    }
                }
            }
        }

        // extract sorted (u, idx); inclusive cumprod; scatter alloc
        float su[8], lp[8]; int sidx[8];
        #pragma unroll
        for (int q = 0; q < 8; ++q) {
            unsigned fb = (unsigned)(key[q] >> 32);
            fb = (fb & 0x80000000u) ? (fb ^ 0x80000000u) : ~fb;
            su[q]   = __uint_as_float(fb);
            sidx[q] = (int)(key[q] & 0xffffffffu);
        }
        float run = 1.f;
        #pragma unroll
        for (int q = 0; q < 8; ++q) { run *= su[q]; lp[q] = run; }
        scan[t] = run;
        __syncthreads();
        for (int off = 1; off < 256; off <<= 1) {
            float val = scan[t];
            float oth = (t >= off) ? scan[t - off] : 1.0f;
            __syncthreads();
            scan[t] = val * oth;
            __syncthreads();
        }
        float pref = (t > 0) ? scan[t - 1] : 1.0f;
        #pragma unroll
        for (int q = 0; q < 8; ++q)
            alloc_ws[(size_t)b*M + sidx[q]] = (1.0f - su[q]) * (pref * lp[q]);

    } else {
        // ================= scores path: s1 = v.mem + c1, s2 = u2.mem =================
        const int blk = blockIdx.x - B;
        const int b = blk >> 4, chunk = blk & 15;
        const int l = t & 15, g = t >> 4;
        float v8[8], u8[8];
        {
            const float* vb = v_ws  + (size_t)b*E + l*8;
            const float* ub = u2_ws + (size_t)b*E + l*8;
            #pragma unroll
            for (int j = 0; j < 8; ++j) { v8[j] = vb[j]; u8[j] = ub[j]; }
        }
        const float cc1 = c1_ws[b];
        const size_t mbase = (size_t)b*M*E;
        const int row0 = chunk*128 + g;
        for (int it = 0; it < 8; ++it) {
            int row = row0 + it*16;
            float m8[8]; ld8(mem, mbase + (size_t)row*E + l*8, bf, m8);
            float p1 = 0.f, p2 = 0.f;
            #pragma unroll
            for (int j = 0; j < 8; ++j) { p1 += m8[j]*v8[j]; p2 += m8[j]*u8[j]; }
            #pragma unroll
            for (int mask = 8; mask > 0; mask >>= 1) {
                p1 += __shfl_xor(p1, mask, 16);
                p2 += __shfl_xor(p2, mask, 16);
            }
            if (l == 0) {
                s1[(size_t)b*M + row] = p1 + cc1;
                s2[(size_t)b*M + row] = p2;
            }
        }
    }
}

// ---------- k4: per-batch softmax STATS only -> (gmax1, inv1, gmax2, inv2) ----------
__global__ __launch_bounds__(256) void k4_stats(
    const float* __restrict__ s1, const float* __restrict__ s2,
    const float* __restrict__ alloc_ws,
    const float* __restrict__ c2_ws, const float* __restrict__ d2_ws,
    float* __restrict__ stats_ws)
{
    __shared__ float r4[4];
    const int b = blockIdx.x, t = threadIdx.x;
    const float* s1b = s1 + (size_t)b*M;
    const float* s2b = s2 + (size_t)b*M;

    float sv[8];
    float lmax = -3.4e38f;
    #pragma unroll
    for (int s = 0; s < 8; ++s) { sv[s] = s1b[s*256 + t]; lmax = fmaxf(lmax, sv[s]); }
    const float gmax1 = bmax4(lmax, r4, t);
    float lsum = 0.f;
    #pragma unroll
    for (int s = 0; s < 8; ++s) { float e = expf(sv[s] - gmax1); sv[s] = e; lsum += e; }
    const float inv1 = 1.0f / bsum4(lsum, r4, t);

    const float dd = d2_ws[b], cc = c2_ws[b];
    float rs[8];
    lmax = -3.4e38f;
    #pragma unroll
    for (int s = 0; s < 8; ++s) {
        int m = s*256 + t;
        float wv = 0.5f * (sv[s] * inv1 + alloc_ws[(size_t)b*M + m]);
        rs[s] = s2b[m] + wv * dd + cc;
        lmax = fmaxf(lmax, rs[s]);
    }
    const float gmax2 = bmax4(lmax, r4, t);
    lsum = 0.f;
    #pragma unroll
    for (int s = 0; s < 8; ++s) lsum += expf(rs[s] - gmax2);
    const float inv2 = 1.0f / bsum4(lsum, r4, t);

    if (t == 0) {
        stats_ws[b*4 + 0] = gmax1;
        stats_ws[b*4 + 1] = inv1;
        stats_ws[b*4 + 2] = gmax2;
        stats_ws[b*4 + 3] = inv2;
    }
}

// ---------- k5: per (b,chunk) reversed. Chunk-local w/wr from stats; writes W/WR slice;
//              stream new_mem = mem + w*emb; pooled partials ----------
__global__ __launch_bounds__(256) void k5_update(
    const void* __restrict__ mem, const void* __restrict__ us,
    const float* __restrict__ emb_ws, const float* __restrict__ alloc_ws,
    const float* __restrict__ s1, const float* __restrict__ s2,
    const float* __restrict__ c2_ws, const float* __restrict__ d2_ws,
    const float* __restrict__ stats_ws,
    float* __restrict__ pooled_p, void* __restrict__ dout)
{
    __shared__ float wsh[128];
    __shared__ float wrsh[128];
    __shared__ float pw[4][E];
    const int bf = detect_bf(us);
    const int rblk = (B*16 - 1) - (int)blockIdx.x;   // reversed vs kB scores for L3 reuse
    const int b = rblk >> 4, chunk = rblk & 15;
    const int t = threadIdx.x, l = t & 15, g = t >> 4;

    const float gmax1 = stats_ws[b*4 + 0], inv1 = stats_ws[b*4 + 1];
    const float gmax2 = stats_ws[b*4 + 2], inv2 = stats_ws[b*4 + 3];
    const float dd = d2_ws[b], cc = c2_ws[b];

    // chunk-local w/wr (128 rows), write output slices
    if (t < 128) {
        const size_t m = (size_t)b*M + chunk*128 + t;
        float e1  = expf(s1[m] - gmax1);
        float wv  = 0.5f * (e1 * inv1 + alloc_ws[m]);
        float rsv = s2[m] + wv * dd + cc;
        float wrv = expf(rsv - gmax2) * inv2;
        wsh[t]  = wv;
        wrsh[t] = wrv;
        st1(dout, OFF_W  + m, bf, wv);
        st1(dout, OFF_WR + m, bf, wrv);
    }
    __syncthreads();

    // stream: new_mem = mem + w*emb; pooled partial
    float e8[8];
    {
        const float* eb = emb_ws + (size_t)b*E + l*8;
        #pragma unroll
        for (int j = 0; j < 8; ++j) e8[j] = eb[j];
    }
    float acc[8] = {0,0,0,0,0,0,0,0};
    const size_t mbase = (size_t)b*M*E;
    for (int it = 0; it < 8; ++it) {
        int lr = g + it*16;                     // local row in chunk [0,128)
        int row = chunk*128 + lr;
        size_t off = mbase + (size_t)row*E + l*8;
        float m8[8]; ld8(mem, off, bf, m8);
        const float wv  = wsh[lr];
        const float wrv = wrsh[lr];
        float n8[8];
        #pragma unroll
        for (int j = 0; j < 8; ++j) {
            n8[j] = m8[j] + wv * e8[j];
            acc[j] += wrv * n8[j];
        }
        st8(dout, OFF_NM + off, bf, n8);          // new_memory output
    }
    // reduce over the 16 g-groups: 4 in-wave via shfl, 4 waves via LDS
    #pragma unroll
    for (int j = 0; j < 8; ++j) {
        acc[j] += __shfl_xor(acc[j], 16, 64);
        acc[j] += __shfl_xor(acc[j], 32, 64);
    }
    const int wid = t >> 6;
    if ((t & 63) < 16) {
        const int l0 = t & 15;
        #pragma unroll
        for (int j = 0; j < 8; ++j) pw[wid][l0*8 + j] = acc[j];
    }
    __syncthreads();
    if (t < E)
        pooled_p[((size_t)b*16 + chunk)*E + t] = pw[0][t] + pw[1][t] + pw[2][t] + pw[3][t];
}

// ---------- kO: per batch: pooled = sum chunks; output = pooled @ O_w^T + O_b ----------
__global__ __launch_bounds__(512) void kO_out(
    const float* __restrict__ pooled_p,
    const void* __restrict__ O_w, const void* __restrict__ O_b,
    const void* __restrict__ us, void* __restrict__ dout)
{
    __shared__ float ps[E];
    const int bf = detect_bf(us);
    const int b = blockIdx.x, t = threadIdx.x;
    if (t < E) {
        float s = 0.f;
        #pragma unroll
        for (int c = 0; c < 16; ++c) s += pooled_p[((size_t)b*16 + c)*E + t];
        ps[t] = s;
    }
    __syncthreads();
    float a = 0.f;
    for (int c = 0; c < E/8; ++c) {
        float m8[8]; ld8(O_w, (size_t)t*E + c*8, bf, m8);
        #pragma unroll
        for (int j = 0; j < 8; ++j) a += m8[j] * ps[c*8 + j];
    }
    a += ldf(O_b, t, bf);
    st1(dout, OFF_Y + (size_t)b*OUTd + t, bf, a);
}

extern "C" void kernel_launch(void* const* d_in, const int* in_sizes, int n_in,
                              void* d_out, int out_size, void* d_ws, size_t ws_size,
                              hipStream_t stream)
{
    const void* rw  = d_in[0];
    const void* ww  = d_in[1];
    const void* us  = d_in[2];
    const void* fg  = d_in[3];
    const void* x   = d_in[4];
    const void* qy  = d_in[5];
    const void* mem = d_in[6];
    const void* I_w = d_in[7];
    const void* I_b = d_in[8];
    const void* W1w = d_in[9];
    const void* W1b = d_in[10];
    const void* W2w = d_in[11];
    const void* W2b = d_in[12];
    const void* R1w = d_in[13];
    const void* R1b = d_in[14];
    const void* R2w = d_in[15];
    const void* R2b = d_in[16];
    const void* O_w = d_in[17];
    const void* O_b = d_in[18];

    float* fbase    = (float*)d_ws;
    float* emb_ws   = fbase;                          // B*E
    float* v_ws     = emb_ws + (size_t)B*E;           // B*E
    float* u2_ws    = v_ws   + (size_t)B*E;           // B*E
    float* c1_ws    = u2_ws  + (size_t)B*E;           // B
    float* c2_ws    = c1_ws  + B;                     // B
    float* d2_ws    = c2_ws  + B;                     // B
    float* stats_ws = d2_ws  + B;                     // 4*B
    float* alloc_ws = stats_ws + (size_t)4*B;         // B*M
    float* s1_ws    = alloc_ws + (size_t)B*M;         // B*M
    float* s2_ws    = s1_ws    + (size_t)B*M;         // B*M
    float* pooled_p = s2_ws    + (size_t)B*M;         // B*16*E == B*M

    k1_pre  <<<B,        256, 0, stream>>>(x, qy, I_w, I_b, W1w, W1b, W2w, W2b,
                                           R1w, R1b, R2w, R2b, us,
                                           emb_ws, v_ws, u2_ws, c1_ws, c2_ws, d2_ws);
    kB_alloc_scores<<<B + B*16, 256, 0, stream>>>(rw, ww, us, fg, mem,
                                           v_ws, u2_ws, c1_ws,
                                           alloc_ws, s1_ws, s2_ws, d_out);
    k4_stats<<<B,        256, 0, stream>>>(s1_ws, s2_ws, alloc_ws, c2_ws, d2_ws,
                                           stats_ws);
    k5_update<<<B*16,    256, 0, stream>>>(mem, us, emb_ws, alloc_ws, s1_ws, s2_ws,
                                           c2_ws, d2_ws, stats_ws, pooled_p, d_out);
    kO_out  <<<B,        512, 0, stream>>>(pooled_p, O_w, O_b, us, d_out);
}